// Round 2
// baseline (1327.740 us; speedup 1.0000x reference)
//
#include <hip/hip_runtime.h>

typedef __bf16 bf16;
using bf16x8 = __attribute__((ext_vector_type(8))) __bf16;
using bf16x4 = __attribute__((ext_vector_type(4))) __bf16;
using f32x4  = __attribute__((ext_vector_type(4))) float;
using u32x4  = __attribute__((ext_vector_type(4))) unsigned int;

#define DEV __device__ __forceinline__

DEV float gelu_f(float x){ return 0.5f*x*(1.0f+erff(x*0.7071067811865475f)); }
DEV float sigm_f(float x){ return 1.0f/(1.0f+expf(-x)); }

DEV void gload16(const bf16* g, bf16* l){
    __builtin_amdgcn_global_load_lds(
        (const __attribute__((address_space(1))) void*)g,
        (__attribute__((address_space(3))) void*)l, 16, 0, 0);
}

// ---------------------------------------------------------------------------
// Tiled bf16 MFMA GEMM:  C[M,N] = A[M,K] @ B^T[N,K]^T   (B given as N x K)
// m97 structure: 128x128 tile, BK=64, 4 waves (2x2), 16x16x32 MFMA,
// global_load_lds width=16 staging, linear LDS, M-inner + XCD-swizzled blocks.
// ---------------------------------------------------------------------------
enum { EPI_ADJ=0, EPI_BF16=1, EPI_GELU_BIAS=2, EPI_XUPD=3, EPI_BIAS_F32=4, EPI_F32=5 };

template<int EPI>
__global__ __launch_bounds__(256, 2)
void gemm_bt(const bf16* __restrict__ A, const bf16* __restrict__ B,
             int M, int N, int K, void* __restrict__ Cout, int ldc,
             const float* __restrict__ bias, const float* __restrict__ scal, int sidx,
             float* __restrict__ xu0, float* __restrict__ xu1)
{
    const int nbm = M >> 7, nbn = N >> 7;
    const int nwg = nbm * nbn;
    int wg = blockIdx.x;
    const int cpx = nwg >> 3;                 // all grids here are %8==0 -> bijective
    wg = (wg & 7) * cpx + (wg >> 3);          // T1: contiguous chunk per XCD
    const int by = wg % nbm;                  // M inner: B column-panel reused across
    const int bx = wg / nbm;                  //          consecutive blocks
    const int tid  = threadIdx.x;
    const int lane = tid & 63;
    const int wid  = tid >> 6;
    const int wr = wid >> 1, wc = wid & 1;    // 2x2 wave grid, each wave 64x64

    __shared__ bf16 lA[128*64];
    __shared__ bf16 lB[128*64];

    f32x4 acc[4][4] = {};

    const int lda = K, ldb = K;
    // staging: thread tid loads 16B at row (i*32 + tid/8), 16B-chunk (tid&7).
    // LDS dest is linear: byte = i*4096 + wid*1024 + lane*16  (wave-uniform base).
    const long aoff = (long)(by*128 + (tid>>3)) * lda + (tid&7)*8;
    const long boff = (long)(bx*128 + (tid>>3)) * ldb + (tid&7)*8;
    bf16* lAw = lA + wid*512;                 // + i*2048 elems per round
    bf16* lBw = lB + wid*512;

    const int fr = lane & 15, fq = lane >> 4;
    int aroff[4], broff[4];
#pragma unroll
    for (int mi=0;mi<4;mi++) aroff[mi] = (wr*64 + mi*16 + fr)*64;
#pragma unroll
    for (int ni=0;ni<4;ni++) broff[ni] = (wc*64 + ni*16 + fr)*64;

    for (int kt = 0; kt < K; kt += 64) {
        __syncthreads();                      // WAR: previous tile's reads done
#pragma unroll
        for (int i=0;i<4;i++){
            gload16(A + aoff + (long)i*32*lda + kt, lAw + i*2048);
            gload16(B + boff + (long)i*32*ldb + kt, lBw + i*2048);
        }
        __syncthreads();                      // drains vmcnt -> tile visible
#pragma unroll
        for (int ks=0; ks<2; ks++){
            bf16x8 af[4], bfr[4];
            const int sa = (ks*4 + fq)*8;
#pragma unroll
            for (int mi=0;mi<4;mi++) af[mi]  = *(const bf16x8*)&lA[aroff[mi] + sa];
#pragma unroll
            for (int ni=0;ni<4;ni++) bfr[ni] = *(const bf16x8*)&lB[broff[ni] + sa];
#pragma unroll
            for (int mi=0;mi<4;mi++)
#pragma unroll
                for (int ni=0;ni<4;ni++)
                    acc[mi][ni] = __builtin_amdgcn_mfma_f32_16x16x32_bf16(
                        af[mi], bfr[ni], acc[mi][ni], 0, 0, 0);
        }
    }

    float thr = 0.f;
    if constexpr (EPI==EPI_ADJ) thr = scal[sidx];

#pragma unroll
    for (int mi=0;mi<4;mi++){
#pragma unroll
        for (int ni=0;ni<4;ni++){
            const int col = bx*128 + wc*64 + ni*16 + fr;
#pragma unroll
            for (int r=0;r<4;r++){
                const int row = by*128 + wr*64 + mi*16 + fq*4 + r;
                const float v = acc[mi][ni][r];
                const long ci = (long)row*ldc + col;
                if constexpr (EPI==EPI_ADJ)       ((bf16*)Cout)[ci] = (bf16)sigm_f(10.f*(v - thr));
                else if constexpr (EPI==EPI_BF16) ((bf16*)Cout)[ci] = (bf16)v;
                else if constexpr (EPI==EPI_GELU_BIAS) ((bf16*)Cout)[ci] = (bf16)gelu_f(v + bias[col]);
                else if constexpr (EPI==EPI_BIAS_F32)  ((float*)Cout)[ci] = v + bias[col];
                else if constexpr (EPI==EPI_F32)       ((float*)Cout)[ci] = v;
                else if constexpr (EPI==EPI_XUPD){
                    const float u = 0.2f*(v + bias[col]);
                    xu0[ci] += u;  xu1[ci] += u;
                }
            }
        }
    }
}

// ---------------------------------------------------------------------------
// small kernels
// ---------------------------------------------------------------------------
__global__ void prep_kernel(const float* __restrict__ cs,
                            const float* __restrict__ W1, const float* __restrict__ b1,
                            const float* __restrict__ W2, const float* __restrict__ b2,
                            float* __restrict__ thrs)
{
    __shared__ float cp[1024];
    __shared__ float part[8][32];
    __shared__ float h[32];
    const int tid = threadIdx.x;
    for (int j = tid; j < 1024; j += 256){
        float s = 0.f;
#pragma unroll
        for (int r = 0; r < 8; r++) s += cs[r*1024 + j];
        cp[j] = s * 0.125f;
    }
    __syncthreads();
    const int t = tid & 31, g = tid >> 5;
    float p = 0.f;
    for (int j = g*128; j < g*128+128; j++) p += cp[j] * W1[j*32 + t];
    part[g][t] = p;
    __syncthreads();
    if (tid < 32){
        float s = b1[tid];
#pragma unroll
        for (int q=0;q<8;q++) s += part[q][tid];
        h[tid] = gelu_f(s);
    }
    __syncthreads();
    if (tid < 4){
        float z = b2[tid];
        for (int k=0;k<32;k++) z += h[k]*W2[k*4 + tid];
        thrs[tid] = sigm_f(z);
    }
    if (tid == 4) thrs[4] = 0.5f;   // betti threshold
}

__global__ void embed_kernel(const int* __restrict__ tok, const float* __restrict__ emb,
                             const float* __restrict__ pos, float* __restrict__ x)
{
    const long i = (long)blockIdx.x*256 + threadIdx.x;  // f32x4 index, 1,048,576 total
    const int  d4 = i & 255;
    const long bt = i >> 8;            // 0..4095
    const int  t  = (int)(bt & 2047);
    const int  token = tok[bt];
    f32x4 e = *(const f32x4*)(emb + (long)token*1024 + d4*4);
    f32x4 p = *(const f32x4*)(pos + (long)t*1024 + d4*4);
    *(f32x4*)(x + i*4) = e + p;
}

__global__ void transpose_f2b(const float* __restrict__ in, int ldin,
                              bf16* __restrict__ out, int ldout, int R, int C)
{
    __shared__ float tile[32][33];
    const int nbx = C >> 5;
    const int bx = blockIdx.x % nbx, by = blockIdx.x / nbx;
    const int tx = threadIdx.x & 31, ty = threadIdx.x >> 5; // 32x8
#pragma unroll
    for (int i=0;i<32;i+=8)
        tile[ty+i][tx] = in[(long)(by*32+ty+i)*ldin + bx*32+tx];
    __syncthreads();
#pragma unroll
    for (int i=0;i<32;i+=8)
        out[(long)(bx*32+ty+i)*ldout + by*32+tx] = (bf16)tile[tx][ty+i];
}

__global__ void rownorm_kernel(const float* __restrict__ x, bf16* __restrict__ xn,
                               bf16* __restrict__ x0b, int ld0)
{
    const long t = blockIdx.x; const int tid = threadIdx.x;
    f32x4 v = *(const f32x4*)(x + t*1024 + tid*4);
    float s = v.x*v.x + v.y*v.y + v.z*v.z + v.w*v.w;
#pragma unroll
    for (int o=32;o>0;o>>=1) s += __shfl_down(s, o);
    __shared__ float red[4];
    if ((tid&63)==0) red[tid>>6] = s;
    __syncthreads();
    const float tot = red[0]+red[1]+red[2]+red[3];
    const float inv = 1.0f / fmaxf(sqrtf(tot), 1e-12f);
    bf16x4 a, b;
    a[0]=(bf16)(v.x*inv); a[1]=(bf16)(v.y*inv); a[2]=(bf16)(v.z*inv); a[3]=(bf16)(v.w*inv);
    b[0]=(bf16)v.x; b[1]=(bf16)v.y; b[2]=(bf16)v.z; b[3]=(bf16)v.w;
    *(bf16x4*)(xn  + t*1024 + tid*4) = a;
    *(bf16x4*)(x0b + t*ld0  + tid*4) = b;
}

__global__ void degree_kernel(const bf16* __restrict__ adj, float* __restrict__ deg)
{
    const long t = blockIdx.x; const int tid = threadIdx.x;
    bf16x8 v = *(const bf16x8*)(adj + t*2048 + tid*8);
    float s = 0.f;
#pragma unroll
    for (int j=0;j<8;j++) s += (float)v[j];
#pragma unroll
    for (int o=32;o>0;o>>=1) s += __shfl_down(s, o);
    __shared__ float red[4];
    if ((tid&63)==0) red[tid>>6] = s;
    __syncthreads();
    if (tid==0) deg[t] = red[0]+red[1]+red[2]+red[3];
}

__global__ void betti_kernel(const float* __restrict__ deg, float* __restrict__ betti)
{
    const int tid = threadIdx.x;
    float s = 0.f, c = 0.f;
#pragma unroll
    for (int i=0;i<8;i++){
        const float d = deg[tid*8 + i];
        s += d;  c += (d < 0.5f) ? 1.f : 0.f;
    }
#pragma unroll
    for (int o=32;o>0;o>>=1){ s += __shfl_down(s,o); c += __shfl_down(c,o); }
    __shared__ float ss[4], cc[4];
    if ((tid&63)==0){ ss[tid>>6]=s; cc[tid>>6]=c; }
    __syncthreads();
    if (tid==0){
        const float S = ss[0]+ss[1]+ss[2]+ss[3];
        const float C = cc[0]+cc[1]+cc[2]+cc[3];
        const float ne = 0.5f*S;
        const float b1 = ne - 2048.f + C + 1.f;
        betti[0] = C;
        betti[1] = b1 > 0.f ? b1 : 0.f;
    }
}

// b1eff[j] = int_b1[j] + beta0*int_W1[1024][j] + beta1*int_W1[1025][j]
__global__ void b1eff_kernel(const float* __restrict__ ib1, const float* __restrict__ iW1,
                             const float* __restrict__ betti, float* __restrict__ out)
{
    const int j = blockIdx.x*256 + threadIdx.x;
    out[j] = ib1[j] + betti[0]*iW1[(long)1024*2048 + j] + betti[1]*iW1[(long)1025*2048 + j];
}

__global__ void f2b_kernel(const float* __restrict__ in, bf16* __restrict__ out)
{
    const long i = (long)blockIdx.x*256 + threadIdx.x;
    f32x4 a = *(const f32x4*)(in + i*8);
    f32x4 c = *(const f32x4*)(in + i*8 + 4);
    bf16x8 o;
    o[0]=(bf16)a.x; o[1]=(bf16)a.y; o[2]=(bf16)a.z; o[3]=(bf16)a.w;
    o[4]=(bf16)c.x; o[5]=(bf16)c.y; o[6]=(bf16)c.z; o[7]=(bf16)c.w;
    *(bf16x8*)(out + i*8) = o;
}

__global__ void ln_kernel(const float* __restrict__ y, const float* __restrict__ g,
                          const float* __restrict__ b, bf16* __restrict__ out)
{
    const long t = blockIdx.x; const int tid = threadIdx.x;
    f32x4 v = *(const f32x4*)(y + t*1024 + tid*4);
    float s  = v.x+v.y+v.z+v.w;
    float s2 = v.x*v.x+v.y*v.y+v.z*v.z+v.w*v.w;
#pragma unroll
    for (int o=32;o>0;o>>=1){ s += __shfl_down(s,o); s2 += __shfl_down(s2,o); }
    __shared__ float ss[4], qq[4];
    if ((tid&63)==0){ ss[tid>>6]=s; qq[tid>>6]=s2; }
    __syncthreads();
    const float S = ss[0]+ss[1]+ss[2]+ss[3], Q = qq[0]+qq[1]+qq[2]+qq[3];
    const float mu  = S * (1.f/1024.f);
    const float var = Q * (1.f/1024.f) - mu*mu;
    const float inv = rsqrtf(var + 1e-5f);
    f32x4 gv = *(const f32x4*)(g + tid*4);
    f32x4 bv = *(const f32x4*)(b + tid*4);
    bf16x4 o;
    o[0] = (bf16)((v.x - mu)*inv*gv.x + bv.x);
    o[1] = (bf16)((v.y - mu)*inv*gv.y + bv.y);
    o[2] = (bf16)((v.z - mu)*inv*gv.z + bv.z);
    o[3] = (bf16)((v.w - mu)*inv*gv.w + bv.w);
    *(bf16x4*)(out + t*1024 + tid*4) = o;
}

// ---------------------------------------------------------------------------
extern "C" void kernel_launch(void* const* d_in, const int* in_sizes, int n_in,
                              void* d_out, int out_size, void* d_ws, size_t ws_size,
                              hipStream_t stream)
{
    const int*   tokens = (const int*)  d_in[0];
    const float* cstate = (const float*)d_in[1];
    const float* embedW = (const float*)d_in[2];
    const float* posW   = (const float*)d_in[3];
    const float* thrW1  = (const float*)d_in[8];
    const float* thrb1  = (const float*)d_in[9];
    const float* thrW2  = (const float*)d_in[10];
    const float* thrb2  = (const float*)d_in[11];
    const float* simpW1 = (const float*)d_in[12];
    const float* simpb1 = (const float*)d_in[13];
    const float* simpW2 = (const float*)d_in[14];
    const float* simpb2 = (const float*)d_in[15];
    const float* intW1  = (const float*)d_in[16];
    const float* intb1  = (const float*)d_in[17];
    const float* intW2  = (const float*)d_in[18];
    const float* intb2  = (const float*)d_in[19];
    const float* lng    = (const float*)d_in[20];
    const float* lnb    = (const float*)d_in[21];
    const float* headW  = (const float*)d_in[22];
    float* out = (float*)d_out;

    size_t off = 0;
    auto carve = [&](size_t bytes) -> void* {
        void* p = (char*)d_ws + off;
        off += (bytes + 255) & ~(size_t)255;
        return p;
    };
    float* x_f32   = (float*)carve(16777216);   // [2][2048][1024] f32
    bf16*  xn      = (bf16*) carve(4194304);    // [2048][1024]
    bf16*  x0T     = (bf16*) carve(4194304);    // [1024][2048]  (contiguous after xn)
    bf16*  comb    = (bf16*) carve(8388608);    // [2048][2048]
    bf16*  adj     = (bf16*) carve(8388608);    // [2048][2048]  (contiguous after comb)
    bf16*  h1      = (bf16*) carve(4194304);    // [2048][1024]
    bf16*  xb      = (bf16*) carve(8388608);    // [4096][1024]
    bf16*  w1T     = (bf16*) carve(16777216);   // [4][1024][2048]
    bf16*  w2T     = (bf16*) carve(8388608);    // [4][1024][1024]
    bf16*  i1T     = (bf16*) carve(4194304);    // [2048][1024]
    bf16*  i2T     = (bf16*) carve(4194304);    // [1024][2048]
    bf16*  hT      = (bf16*) carve(65536000);   // [32000][1024]
    float* degree  = (float*)carve(8192);
    float* b1eff   = (float*)carve(8192);
    float* thrs    = (float*)carve(64);
    float* betti   = (float*)carve(64);
    // aliases (lifetimes disjoint):
    bf16*  h2  = comb;     // [4096][2048] over comb+adj (dead after betti/degree)
    float* yv  = x_f32;    // [4096][1024] f32 (x_f32 dead after f2b)
    bf16*  xln = xn;       // [4096][1024] over xn+x0T (dead after betti sim GEMM)

    const dim3 blk(256);

    prep_kernel<<<1, blk, 0, stream>>>(cstate, thrW1, thrb1, thrW2, thrb2, thrs);
    embed_kernel<<<4096, blk, 0, stream>>>(tokens, embedW, posW, x_f32);

    // weight transposes (f32 -> bf16, N x K layout)
    for (int l=0;l<4;l++)
        transpose_f2b<<<(1024/32)*(2048/32), blk, 0, stream>>>(
            simpW1 + (long)l*2048*1024, 1024, w1T + (long)l*1024*2048, 2048, 2048, 1024);
    for (int l=0;l<4;l++)
        transpose_f2b<<<(1024/32)*(1024/32), blk, 0, stream>>>(
            simpW2 + (long)l*1024*1024, 1024, w2T + (long)l*1024*1024, 1024, 1024, 1024);
    transpose_f2b<<<(2048/32)*(1024/32), blk, 0, stream>>>(intW1, 2048, i1T, 1024, 1024, 2048);
    transpose_f2b<<<(1024/32)*(2048/32), blk, 0, stream>>>(intW2, 1024, i2T, 2048, 2048, 1024);
    transpose_f2b<<<(32000/32)*(1024/32), blk, 0, stream>>>(headW, 32000, hT, 1024, 1024, 32000);

    // simplex levels
    for (int l=0;l<4;l++){
        rownorm_kernel<<<2048, blk, 0, stream>>>(x_f32, xn, comb, 2048);
        transpose_f2b<<<(1024/32)*(2048/32), blk, 0, stream>>>(x_f32, 1024, x0T, 2048, 2048, 1024);
        gemm_bt<EPI_ADJ><<<(2048/128)*(2048/128), blk, 0, stream>>>(
            xn, xn, 2048, 2048, 1024, adj, 2048, nullptr, thrs, l, nullptr, nullptr);
        gemm_bt<EPI_BF16><<<(1024/128)*(2048/128), blk, 0, stream>>>(
            adj, x0T, 2048, 1024, 2048, comb + 1024, 2048, nullptr, nullptr, 0, nullptr, nullptr);
        gemm_bt<EPI_GELU_BIAS><<<(1024/128)*(2048/128), blk, 0, stream>>>(
            comb, w1T + (long)l*1024*2048, 2048, 1024, 2048, h1, 1024,
            simpb1 + l*1024, nullptr, 0, nullptr, nullptr);
        gemm_bt<EPI_XUPD><<<(1024/128)*(2048/128), blk, 0, stream>>>(
            h1, w2T + (long)l*1024*1024, 2048, 1024, 1024, nullptr, 1024,
            simpb2 + l*1024, nullptr, 0, x_f32, x_f32 + (long)2048*1024);
    }

    // betti pass
    rownorm_kernel<<<2048, blk, 0, stream>>>(x_f32, xn, comb, 2048);
    gemm_bt<EPI_ADJ><<<(2048/128)*(2048/128), blk, 0, stream>>>(
        xn, xn, 2048, 2048, 1024, adj, 2048, nullptr, thrs, 4, nullptr, nullptr);
    degree_kernel<<<2048, blk, 0, stream>>>(adj, degree);
    betti_kernel<<<1, blk, 0, stream>>>(degree, betti);
    b1eff_kernel<<<8, blk, 0, stream>>>(intb1, intW1, betti, b1eff);

    // integrate + LN + head
    f2b_kernel<<<2048, blk, 0, stream>>>(x_f32, xb);   // 4096x1024 -> bf16
    gemm_bt<EPI_GELU_BIAS><<<(2048/128)*(4096/128), blk, 0, stream>>>(
        xb, i1T, 4096, 2048, 1024, h2, 2048, b1eff, nullptr, 0, nullptr, nullptr);
    gemm_bt<EPI_BIAS_F32><<<(1024/128)*(4096/128), blk, 0, stream>>>(
        h2, i2T, 4096, 1024, 2048, yv, 1024, intb2, nullptr, 0, nullptr, nullptr);
    ln_kernel<<<4096, blk, 0, stream>>>(yv, lng, lnb, xln);
    gemm_bt<EPI_F32><<<(32000/128)*(4096/128), blk, 0, stream>>>(
        xln, hT, 4096, 32000, 1024, out, 32000, nullptr, nullptr, 0, nullptr, nullptr);
}

// Round 3
// 1220.291 us; speedup vs baseline: 1.0881x; 1.0881x over previous
//
#include <hip/hip_runtime.h>

typedef __bf16 bf16;
using bf16x8 = __attribute__((ext_vector_type(8))) __bf16;
using bf16x4 = __attribute__((ext_vector_type(4))) __bf16;
using f32x4  = __attribute__((ext_vector_type(4))) float;
using u32x4  = __attribute__((ext_vector_type(4))) unsigned int;

#define DEV __device__ __forceinline__

DEV float gelu_f(float x){ return 0.5f*x*(1.0f+erff(x*0.7071067811865475f)); }
DEV float sigm_f(float x){ return 1.0f/(1.0f+expf(-x)); }

DEV void gload16(const bf16* g, bf16* l){
    __builtin_amdgcn_global_load_lds(
        (const __attribute__((address_space(1))) void*)g,
        (__attribute__((address_space(3))) void*)l, 16, 0, 0);
}

// ---------------------------------------------------------------------------
// Tiled bf16 MFMA GEMM:  C[M,N] = A[M,K] @ B^T[N,K]^T   (B given as N x K)
// m97 structure: 128x128 tile, BK=64, 4 waves (2x2), 16x16x32 MFMA,
// global_load_lds width=16 staging with LINEAR LDS dest + INVERSE-swizzled
// global source + swizzled ds_read (rule #21 both-sides pattern, m201).
// ---------------------------------------------------------------------------
enum { EPI_ADJ=0, EPI_BF16=1, EPI_GELU_BIAS=2, EPI_XUPD=3, EPI_BIAS_F32=4, EPI_F32=5 };

template<int EPI>
__global__ __launch_bounds__(256, 2)
void gemm_bt(const bf16* __restrict__ A, const bf16* __restrict__ B,
             int M, int N, int K, void* __restrict__ Cout, int ldc,
             const float* __restrict__ bias, const float* __restrict__ scal, int sidx,
             float* __restrict__ xu0, float* __restrict__ xu1)
{
    const int nbm = M >> 7, nbn = N >> 7;
    const int nwg = nbm * nbn;
    int wg = blockIdx.x;
    const int cpx = nwg >> 3;                 // all grids here are %8==0 -> bijective
    wg = (wg & 7) * cpx + (wg >> 3);          // T1: contiguous chunk per XCD
    const int by = wg % nbm;                  // M inner: B column-panel reused across
    const int bx = wg / nbm;                  //          consecutive blocks
    const int tid  = threadIdx.x;
    const int lane = tid & 63;
    const int wid  = tid >> 6;
    const int wr = wid >> 1, wc = wid & 1;    // 2x2 wave grid, each wave 64x64

    __shared__ bf16 lA[128*64];
    __shared__ bf16 lB[128*64];

    f32x4 acc[4][4] = {};

    const int lda = K, ldb = K;
    // staging: thread tid fills LDS linear chunk (srow, skc); it must LOAD the
    // global chunk (skc ^ (srow&7)) so that LDS holds the swizzled layout
    // (source permutation == read permutation, involution within 8-chunk rows).
    const int srow = tid >> 3, skc = tid & 7;
    const long aoff = (long)(by*128 + srow) * lda + (skc ^ (srow & 7))*8;
    const long boff = (long)(bx*128 + srow) * ldb + (skc ^ (srow & 7))*8;
    bf16* lAw = lA + wid*512;                 // + i*2048 elems per round
    bf16* lBw = lB + wid*512;

    const int fr = lane & 15, fq = lane >> 4;
    int aroff[4], broff[4];
#pragma unroll
    for (int mi=0;mi<4;mi++) aroff[mi] = (wr*64 + mi*16 + fr)*64;
#pragma unroll
    for (int ni=0;ni<4;ni++) broff[ni] = (wc*64 + ni*16 + fr)*64;

    for (int kt = 0; kt < K; kt += 64) {
        __syncthreads();                      // WAR: previous tile's reads done
#pragma unroll
        for (int i=0;i<4;i++){
            gload16(A + aoff + (long)i*32*lda + kt, lAw + i*2048);
            gload16(B + boff + (long)i*32*ldb + kt, lBw + i*2048);
        }
        __syncthreads();                      // drains vmcnt -> tile visible
#pragma unroll
        for (int ks=0; ks<2; ks++){
            bf16x8 af[4], bfr[4];
            const int sa = (((ks*4 + fq) ^ (fr & 7)) << 3);   // read-side swizzle
#pragma unroll
            for (int mi=0;mi<4;mi++) af[mi]  = *(const bf16x8*)&lA[aroff[mi] + sa];
#pragma unroll
            for (int ni=0;ni<4;ni++) bfr[ni] = *(const bf16x8*)&lB[broff[ni] + sa];
#pragma unroll
            for (int mi=0;mi<4;mi++)
#pragma unroll
                for (int ni=0;ni<4;ni++)
                    acc[mi][ni] = __builtin_amdgcn_mfma_f32_16x16x32_bf16(
                        af[mi], bfr[ni], acc[mi][ni], 0, 0, 0);
        }
    }

    float thr = 0.f;
    if constexpr (EPI==EPI_ADJ) thr = scal[sidx];

#pragma unroll
    for (int mi=0;mi<4;mi++){
#pragma unroll
        for (int ni=0;ni<4;ni++){
            const int col = bx*128 + wc*64 + ni*16 + fr;
#pragma unroll
            for (int r=0;r<4;r++){
                const int row = by*128 + wr*64 + mi*16 + fq*4 + r;
                const float v = acc[mi][ni][r];
                const long ci = (long)row*ldc + col;
                if constexpr (EPI==EPI_ADJ)       ((bf16*)Cout)[ci] = (bf16)sigm_f(10.f*(v - thr));
                else if constexpr (EPI==EPI_BF16) ((bf16*)Cout)[ci] = (bf16)v;
                else if constexpr (EPI==EPI_GELU_BIAS) ((bf16*)Cout)[ci] = (bf16)gelu_f(v + bias[col]);
                else if constexpr (EPI==EPI_BIAS_F32)  ((float*)Cout)[ci] = v + bias[col];
                else if constexpr (EPI==EPI_F32)       ((float*)Cout)[ci] = v;
                else if constexpr (EPI==EPI_XUPD){
                    const float u = 0.2f*(v + bias[col]);
                    xu0[ci] += u;  xu1[ci] += u;
                }
            }
        }
    }
}

// ---------------------------------------------------------------------------
// small kernels
// ---------------------------------------------------------------------------
__global__ void prep_kernel(const float* __restrict__ cs,
                            const float* __restrict__ W1, const float* __restrict__ b1,
                            const float* __restrict__ W2, const float* __restrict__ b2,
                            float* __restrict__ thrs)
{
    __shared__ float cp[1024];
    __shared__ float part[8][32];
    __shared__ float h[32];
    const int tid = threadIdx.x;
    for (int j = tid; j < 1024; j += 256){
        float s = 0.f;
#pragma unroll
        for (int r = 0; r < 8; r++) s += cs[r*1024 + j];
        cp[j] = s * 0.125f;
    }
    __syncthreads();
    const int t = tid & 31, g = tid >> 5;
    float p = 0.f;
    for (int j = g*128; j < g*128+128; j++) p += cp[j] * W1[j*32 + t];
    part[g][t] = p;
    __syncthreads();
    if (tid < 32){
        float s = b1[tid];
#pragma unroll
        for (int q=0;q<8;q++) s += part[q][tid];
        h[tid] = gelu_f(s);
    }
    __syncthreads();
    if (tid < 4){
        float z = b2[tid];
        for (int k=0;k<32;k++) z += h[k]*W2[k*4 + tid];
        thrs[tid] = sigm_f(z);
    }
    if (tid == 4) thrs[4] = 0.5f;   // betti threshold
}

__global__ void embed_kernel(const int* __restrict__ tok, const float* __restrict__ emb,
                             const float* __restrict__ pos, float* __restrict__ x)
{
    const long i = (long)blockIdx.x*256 + threadIdx.x;  // f32x4 index, 1,048,576 total
    const int  d4 = i & 255;
    const long bt = i >> 8;            // 0..4095
    const int  t  = (int)(bt & 2047);
    const int  token = tok[bt];
    f32x4 e = *(const f32x4*)(emb + (long)token*1024 + d4*4);
    f32x4 p = *(const f32x4*)(pos + (long)t*1024 + d4*4);
    *(f32x4*)(x + i*4) = e + p;
}

__global__ void transpose_f2b(const float* __restrict__ in, int ldin,
                              bf16* __restrict__ out, int ldout, int R, int C)
{
    __shared__ float tile[32][33];
    const int nbx = C >> 5;
    const int bx = blockIdx.x % nbx, by = blockIdx.x / nbx;
    const int tx = threadIdx.x & 31, ty = threadIdx.x >> 5; // 32x8
#pragma unroll
    for (int i=0;i<32;i+=8)
        tile[ty+i][tx] = in[(long)(by*32+ty+i)*ldin + bx*32+tx];
    __syncthreads();
#pragma unroll
    for (int i=0;i<32;i+=8)
        out[(long)(bx*32+ty+i)*ldout + by*32+tx] = (bf16)tile[tx][ty+i];
}

__global__ void rownorm_kernel(const float* __restrict__ x, bf16* __restrict__ xn,
                               bf16* __restrict__ x0b, int ld0)
{
    const long t = blockIdx.x; const int tid = threadIdx.x;
    f32x4 v = *(const f32x4*)(x + t*1024 + tid*4);
    float s = v.x*v.x + v.y*v.y + v.z*v.z + v.w*v.w;
#pragma unroll
    for (int o=32;o>0;o>>=1) s += __shfl_down(s, o);
    __shared__ float red[4];
    if ((tid&63)==0) red[tid>>6] = s;
    __syncthreads();
    const float tot = red[0]+red[1]+red[2]+red[3];
    const float inv = 1.0f / fmaxf(sqrtf(tot), 1e-12f);
    bf16x4 a, b;
    a[0]=(bf16)(v.x*inv); a[1]=(bf16)(v.y*inv); a[2]=(bf16)(v.z*inv); a[3]=(bf16)(v.w*inv);
    b[0]=(bf16)v.x; b[1]=(bf16)v.y; b[2]=(bf16)v.z; b[3]=(bf16)v.w;
    *(bf16x4*)(xn  + t*1024 + tid*4) = a;
    *(bf16x4*)(x0b + t*ld0  + tid*4) = b;
}

__global__ void degree_kernel(const bf16* __restrict__ adj, float* __restrict__ deg)
{
    const long t = blockIdx.x; const int tid = threadIdx.x;
    bf16x8 v = *(const bf16x8*)(adj + t*2048 + tid*8);
    float s = 0.f;
#pragma unroll
    for (int j=0;j<8;j++) s += (float)v[j];
#pragma unroll
    for (int o=32;o>0;o>>=1) s += __shfl_down(s, o);
    __shared__ float red[4];
    if ((tid&63)==0) red[tid>>6] = s;
    __syncthreads();
    if (tid==0) deg[t] = red[0]+red[1]+red[2]+red[3];
}

__global__ void betti_kernel(const float* __restrict__ deg, float* __restrict__ betti)
{
    const int tid = threadIdx.x;
    float s = 0.f, c = 0.f;
#pragma unroll
    for (int i=0;i<8;i++){
        const float d = deg[tid*8 + i];
        s += d;  c += (d < 0.5f) ? 1.f : 0.f;
    }
#pragma unroll
    for (int o=32;o>0;o>>=1){ s += __shfl_down(s,o); c += __shfl_down(c,o); }
    __shared__ float ss[4], cc[4];
    if ((tid&63)==0){ ss[tid>>6]=s; cc[tid>>6]=c; }
    __syncthreads();
    if (tid==0){
        const float S = ss[0]+ss[1]+ss[2]+ss[3];
        const float C = cc[0]+cc[1]+cc[2]+cc[3];
        const float ne = 0.5f*S;
        const float b1 = ne - 2048.f + C + 1.f;
        betti[0] = C;
        betti[1] = b1 > 0.f ? b1 : 0.f;
    }
}

// b1eff[j] = int_b1[j] + beta0*int_W1[1024][j] + beta1*int_W1[1025][j]
__global__ void b1eff_kernel(const float* __restrict__ ib1, const float* __restrict__ iW1,
                             const float* __restrict__ betti, float* __restrict__ out)
{
    const int j = blockIdx.x*256 + threadIdx.x;
    out[j] = ib1[j] + betti[0]*iW1[(long)1024*2048 + j] + betti[1]*iW1[(long)1025*2048 + j];
}

__global__ void f2b_kernel(const float* __restrict__ in, bf16* __restrict__ out)
{
    const long i = (long)blockIdx.x*256 + threadIdx.x;
    f32x4 a = *(const f32x4*)(in + i*8);
    f32x4 c = *(const f32x4*)(in + i*8 + 4);
    bf16x8 o;
    o[0]=(bf16)a.x; o[1]=(bf16)a.y; o[2]=(bf16)a.z; o[3]=(bf16)a.w;
    o[4]=(bf16)c.x; o[5]=(bf16)c.y; o[6]=(bf16)c.z; o[7]=(bf16)c.w;
    *(bf16x8*)(out + i*8) = o;
}

__global__ void ln_kernel(const float* __restrict__ y, const float* __restrict__ g,
                          const float* __restrict__ b, bf16* __restrict__ out)
{
    const long t = blockIdx.x; const int tid = threadIdx.x;
    f32x4 v = *(const f32x4*)(y + t*1024 + tid*4);
    float s  = v.x+v.y+v.z+v.w;
    float s2 = v.x*v.x+v.y*v.y+v.z*v.z+v.w*v.w;
#pragma unroll
    for (int o=32;o>0;o>>=1){ s += __shfl_down(s,o); s2 += __shfl_down(s2,o); }
    __shared__ float ss[4], qq[4];
    if ((tid&63)==0){ ss[tid>>6]=s; qq[tid>>6]=s2; }
    __syncthreads();
    const float S = ss[0]+ss[1]+ss[2]+ss[3], Q = qq[0]+qq[1]+qq[2]+qq[3];
    const float mu  = S * (1.f/1024.f);
    const float var = Q * (1.f/1024.f) - mu*mu;
    const float inv = rsqrtf(var + 1e-5f);
    f32x4 gv = *(const f32x4*)(g + tid*4);
    f32x4 bv = *(const f32x4*)(b + tid*4);
    bf16x4 o;
    o[0] = (bf16)((v.x - mu)*inv*gv.x + bv.x);
    o[1] = (bf16)((v.y - mu)*inv*gv.y + bv.y);
    o[2] = (bf16)((v.z - mu)*inv*gv.z + bv.z);
    o[3] = (bf16)((v.w - mu)*inv*gv.w + bv.w);
    *(bf16x4*)(out + t*1024 + tid*4) = o;
}

// ---------------------------------------------------------------------------
extern "C" void kernel_launch(void* const* d_in, const int* in_sizes, int n_in,
                              void* d_out, int out_size, void* d_ws, size_t ws_size,
                              hipStream_t stream)
{
    const int*   tokens = (const int*)  d_in[0];
    const float* cstate = (const float*)d_in[1];
    const float* embedW = (const float*)d_in[2];
    const float* posW   = (const float*)d_in[3];
    const float* thrW1  = (const float*)d_in[8];
    const float* thrb1  = (const float*)d_in[9];
    const float* thrW2  = (const float*)d_in[10];
    const float* thrb2  = (const float*)d_in[11];
    const float* simpW1 = (const float*)d_in[12];
    const float* simpb1 = (const float*)d_in[13];
    const float* simpW2 = (const float*)d_in[14];
    const float* simpb2 = (const float*)d_in[15];
    const float* intW1  = (const float*)d_in[16];
    const float* intb1  = (const float*)d_in[17];
    const float* intW2  = (const float*)d_in[18];
    const float* intb2  = (const float*)d_in[19];
    const float* lng    = (const float*)d_in[20];
    const float* lnb    = (const float*)d_in[21];
    const float* headW  = (const float*)d_in[22];
    float* out = (float*)d_out;

    size_t off = 0;
    auto carve = [&](size_t bytes) -> void* {
        void* p = (char*)d_ws + off;
        off += (bytes + 255) & ~(size_t)255;
        return p;
    };
    float* x_f32   = (float*)carve(16777216);   // [2][2048][1024] f32
    bf16*  xn      = (bf16*) carve(4194304);    // [2048][1024]
    bf16*  x0T     = (bf16*) carve(4194304);    // [1024][2048]  (contiguous after xn)
    bf16*  comb    = (bf16*) carve(8388608);    // [2048][2048]
    bf16*  adj     = (bf16*) carve(8388608);    // [2048][2048]  (contiguous after comb)
    bf16*  h1      = (bf16*) carve(4194304);    // [2048][1024]
    bf16*  xb      = (bf16*) carve(8388608);    // [4096][1024]
    bf16*  w1T     = (bf16*) carve(16777216);   // [4][1024][2048]
    bf16*  w2T     = (bf16*) carve(8388608);    // [4][1024][1024]
    bf16*  i1T     = (bf16*) carve(4194304);    // [2048][1024]
    bf16*  i2T     = (bf16*) carve(4194304);    // [1024][2048]
    bf16*  hT      = (bf16*) carve(65536000);   // [32000][1024]
    float* degree  = (float*)carve(8192);
    float* b1eff   = (float*)carve(8192);
    float* thrs    = (float*)carve(64);
    float* betti   = (float*)carve(64);
    // aliases (lifetimes disjoint):
    bf16*  h2  = comb;     // [4096][2048] over comb+adj (dead after betti/degree)
    float* yv  = x_f32;    // [4096][1024] f32 (x_f32 dead after f2b)
    bf16*  xln = xn;       // [4096][1024] over xn+x0T (dead after betti sim GEMM)

    const dim3 blk(256);

    prep_kernel<<<1, blk, 0, stream>>>(cstate, thrW1, thrb1, thrW2, thrb2, thrs);
    embed_kernel<<<4096, blk, 0, stream>>>(tokens, embedW, posW, x_f32);

    // weight transposes (f32 -> bf16, N x K layout)
    for (int l=0;l<4;l++)
        transpose_f2b<<<(1024/32)*(2048/32), blk, 0, stream>>>(
            simpW1 + (long)l*2048*1024, 1024, w1T + (long)l*1024*2048, 2048, 2048, 1024);
    for (int l=0;l<4;l++)
        transpose_f2b<<<(1024/32)*(1024/32), blk, 0, stream>>>(
            simpW2 + (long)l*1024*1024, 1024, w2T + (long)l*1024*1024, 1024, 1024, 1024);
    transpose_f2b<<<(2048/32)*(1024/32), blk, 0, stream>>>(intW1, 2048, i1T, 1024, 1024, 2048);
    transpose_f2b<<<(1024/32)*(2048/32), blk, 0, stream>>>(intW2, 1024, i2T, 2048, 2048, 1024);
    transpose_f2b<<<(32000/32)*(1024/32), blk, 0, stream>>>(headW, 32000, hT, 1024, 1024, 32000);

    // simplex levels
    for (int l=0;l<4;l++){
        rownorm_kernel<<<2048, blk, 0, stream>>>(x_f32, xn, comb, 2048);
        transpose_f2b<<<(1024/32)*(2048/32), blk, 0, stream>>>(x_f32, 1024, x0T, 2048, 2048, 1024);
        gemm_bt<EPI_ADJ><<<(2048/128)*(2048/128), blk, 0, stream>>>(
            xn, xn, 2048, 2048, 1024, adj, 2048, nullptr, thrs, l, nullptr, nullptr);
        gemm_bt<EPI_BF16><<<(1024/128)*(2048/128), blk, 0, stream>>>(
            adj, x0T, 2048, 1024, 2048, comb + 1024, 2048, nullptr, nullptr, 0, nullptr, nullptr);
        gemm_bt<EPI_GELU_BIAS><<<(1024/128)*(2048/128), blk, 0, stream>>>(
            comb, w1T + (long)l*1024*2048, 2048, 1024, 2048, h1, 1024,
            simpb1 + l*1024, nullptr, 0, nullptr, nullptr);
        gemm_bt<EPI_XUPD><<<(1024/128)*(2048/128), blk, 0, stream>>>(
            h1, w2T + (long)l*1024*1024, 2048, 1024, 1024, nullptr, 1024,
            simpb2 + l*1024, nullptr, 0, x_f32, x_f32 + (long)2048*1024);
    }

    // betti pass
    rownorm_kernel<<<2048, blk, 0, stream>>>(x_f32, xn, comb, 2048);
    gemm_bt<EPI_ADJ><<<(2048/128)*(2048/128), blk, 0, stream>>>(
        xn, xn, 2048, 2048, 1024, adj, 2048, nullptr, thrs, 4, nullptr, nullptr);
    degree_kernel<<<2048, blk, 0, stream>>>(adj, degree);
    betti_kernel<<<1, blk, 0, stream>>>(degree, betti);
    b1eff_kernel<<<8, blk, 0, stream>>>(intb1, intW1, betti, b1eff);

    // integrate + LN + head
    f2b_kernel<<<2048, blk, 0, stream>>>(x_f32, xb);   // 4096x1024 -> bf16
    gemm_bt<EPI_GELU_BIAS><<<(2048/128)*(4096/128), blk, 0, stream>>>(
        xb, i1T, 4096, 2048, 1024, h2, 2048, b1eff, nullptr, 0, nullptr, nullptr);
    gemm_bt<EPI_BIAS_F32><<<(1024/128)*(4096/128), blk, 0, stream>>>(
        h2, i2T, 4096, 1024, 2048, yv, 1024, intb2, nullptr, 0, nullptr, nullptr);
    ln_kernel<<<4096, blk, 0, stream>>>(yv, lng, lnb, xln);
    gemm_bt<EPI_F32><<<(32000/128)*(4096/128), blk, 0, stream>>>(
        xln, hT, 4096, 32000, 1024, out, 32000, nullptr, nullptr, 0, nullptr, nullptr);
}

// Round 4
// 1032.210 us; speedup vs baseline: 1.2863x; 1.1822x over previous
//
#include <hip/hip_runtime.h>

typedef __bf16 bf16;
using bf16x8 = __attribute__((ext_vector_type(8))) __bf16;
using bf16x4 = __attribute__((ext_vector_type(4))) __bf16;
using f32x4  = __attribute__((ext_vector_type(4))) float;

#define DEV __device__ __forceinline__

DEV float gelu_f(float x){ return 0.5f*x*(1.0f+erff(x*0.7071067811865475f)); }
DEV float sigm_f(float x){ return 1.0f/(1.0f+expf(-x)); }

DEV void gload16(const bf16* g, bf16* l){
    __builtin_amdgcn_global_load_lds(
        (const __attribute__((address_space(1))) void*)g,
        (__attribute__((address_space(3))) void*)l, 16, 0, 0);
}

// ---------------------------------------------------------------------------
// Pipelined bf16 MFMA GEMM:  C[M,N] = A[M,K] @ B^T   (B given as N x K)
// Counted-vmcnt pipeline (T3/T4): 2 LDS buffers, tile t+2 staged at end of
// iter t, vmcnt(8) at top keeps next tile's loads in flight across barriers.
// Both-sides swizzle (rule #21, verified r3: conflicts=0). T5 setprio around
// MFMA quadrants. BK=64. 16x16x32 MFMA.
// ---------------------------------------------------------------------------
enum { EPI_ADJ=0, EPI_BF16=1, EPI_GELU_BIAS=2, EPI_XUPD=3, EPI_BIAS_F32=4, EPI_F32=5 };

template<int BM,int BN,int WM,int WN,int EPI>
__global__ __launch_bounds__(WM*WN*64, 2)
void gemm_p(const bf16* __restrict__ A, const bf16* __restrict__ B,
            int M, int N, int K, void* __restrict__ Cout, int ldc,
            const float* __restrict__ bias, const float* __restrict__ scal, int sidx,
            float* __restrict__ xu0, float* __restrict__ xu1)
{
    constexpr int THREADS = WM*WN*64;
    constexpr int MR = BM/WM/16, NR = BN/WN/16;   // fragment repeats per wave
    constexpr int ATILE = BM*64, BTILE = BN*64;   // elems per K-tile
    constexpr int RR = THREADS/8;                 // rows per staging round
    __shared__ bf16 sm[2*(ATILE+BTILE)];

    const int nbm = M/BM, nbn = N/BN;
    const int nwg = nbm*nbn;                      // all grids here are %8==0
    int wg = blockIdx.x;
    wg = (wg&7)*(nwg>>3) + (wg>>3);               // T1 XCD swizzle (bijective)
    const int by = wg % nbm, bx = wg / nbm;       // M-inner for B-panel reuse
    const int tid = threadIdx.x, lane = tid&63, wid = tid>>6;
    const int wm = wid / WN, wn = wid % WN;
    const int fr = lane&15, fq = lane>>4;

    // staging: thread fills LDS linear (row=tid>>3 within round, chunk=tid&7);
    // loads pre-swizzled global chunk (skc ^ (row&7)) so LDS holds swizzled
    // layout matching the read-side XOR (involution; RR%8==0 keeps row&7 stable)
    const bf16* Ab = A + (long)(by*BM + (tid>>3))*K + (((tid&7) ^ ((tid>>3)&7))<<3);
    const bf16* Bb = B + (long)(bx*BN + (tid>>3))*K + (((tid&7) ^ ((tid>>3)&7))<<3);

    auto STAGE = [&](int tt, int cb){
        bf16* d = sm + cb*(ATILE+BTILE) + wid*512;   // wave-uniform base
        const long ko = (long)tt*64;
#pragma unroll
        for (int g=0; g<BM/RR; ++g)
            gload16(Ab + (long)g*RR*K + ko, d + g*RR*64);
#pragma unroll
        for (int g=0; g<BN/RR; ++g)
            gload16(Bb + (long)g*RR*K + ko, d + ATILE + g*RR*64);
    };  // 8 VMEM ops per wave per tile

    f32x4 acc[MR][NR] = {};
    const int nt = K >> 6;

    STAGE(0,0);
    STAGE(1,1);

    for (int t=0; t<nt; ++t){
        const bf16* bufA = sm + (t&1)*(ATILE+BTILE);
        const bf16* bufB = bufA + ATILE;
        // tile t landed; next tile's 8 loads stay in flight (counted, T4)
        if (t+1<nt) asm volatile("s_waitcnt vmcnt(8)" ::: "memory");
        else        asm volatile("s_waitcnt vmcnt(0)" ::: "memory");
        __builtin_amdgcn_s_barrier();             // all waves' loads landed
        __builtin_amdgcn_sched_barrier(0);
#pragma unroll
        for (int mh=0; mh<2; ++mh)
#pragma unroll
        for (int nh=0; nh<2; ++nh){
#pragma unroll
            for (int ks=0; ks<2; ++ks){
                bf16x8 af[MR/2], bv[NR/2];
                const int ch = (((ks*4+fq) ^ (fr&7))<<3);   // read-side swizzle
#pragma unroll
                for (int j=0;j<MR/2;++j)
                    af[j] = *(const bf16x8*)&bufA[(wm*(MR*16) + (mh*(MR/2)+j)*16 + fr)*64 + ch];
#pragma unroll
                for (int j=0;j<NR/2;++j)
                    bv[j] = *(const bf16x8*)&bufB[(wn*(NR*16) + (nh*(NR/2)+j)*16 + fr)*64 + ch];
                __builtin_amdgcn_s_setprio(1);
#pragma unroll
                for (int j=0;j<MR/2;++j)
#pragma unroll
                for (int j2=0;j2<NR/2;++j2)
                    acc[mh*(MR/2)+j][nh*(NR/2)+j2] =
                        __builtin_amdgcn_mfma_f32_16x16x32_bf16(af[j], bv[j2],
                            acc[mh*(MR/2)+j][nh*(NR/2)+j2], 0,0,0);
                __builtin_amdgcn_s_setprio(0);
            }
        }
        asm volatile("s_waitcnt lgkmcnt(0)" ::: "memory");  // reads serviced
        __builtin_amdgcn_s_barrier();             // before overwriting buf
        if (t+2<nt) STAGE(t+2, t&1);
    }

    float thr = 0.f;
    if constexpr (EPI==EPI_ADJ) thr = scal[sidx];

#pragma unroll
    for (int mi=0;mi<MR;++mi){
#pragma unroll
        for (int ni=0;ni<NR;++ni){
            const int col = bx*BN + wn*(NR*16) + ni*16 + fr;
#pragma unroll
            for (int r=0;r<4;++r){
                const int row = by*BM + wm*(MR*16) + mi*16 + fq*4 + r;
                const float v = acc[mi][ni][r];
                const long ci = (long)row*ldc + col;
                if constexpr (EPI==EPI_ADJ)       ((bf16*)Cout)[ci] = (bf16)sigm_f(10.f*(v - thr));
                else if constexpr (EPI==EPI_BF16) ((bf16*)Cout)[ci] = (bf16)v;
                else if constexpr (EPI==EPI_GELU_BIAS) ((bf16*)Cout)[ci] = (bf16)gelu_f(v + bias[col]);
                else if constexpr (EPI==EPI_BIAS_F32)  ((float*)Cout)[ci] = v + bias[col];
                else if constexpr (EPI==EPI_F32)       ((float*)Cout)[ci] = v;
                else if constexpr (EPI==EPI_XUPD){
                    const float u = 0.2f*(v + bias[col]);
                    xu0[ci] += u;  xu1[ci] += u;
                }
            }
        }
    }
}

// ---------------------------------------------------------------------------
// small kernels
// ---------------------------------------------------------------------------
__global__ void prep_kernel(const float* __restrict__ cs,
                            const float* __restrict__ W1, const float* __restrict__ b1,
                            const float* __restrict__ W2, const float* __restrict__ b2,
                            float* __restrict__ thrs)
{
    __shared__ float cp[1024];
    __shared__ float part[8][32];
    __shared__ float h[32];
    const int tid = threadIdx.x;
    for (int j = tid; j < 1024; j += 256){
        float s = 0.f;
#pragma unroll
        for (int r = 0; r < 8; r++) s += cs[r*1024 + j];
        cp[j] = s * 0.125f;
    }
    __syncthreads();
    const int t = tid & 31, g = tid >> 5;
    float p = 0.f;
    for (int j = g*128; j < g*128+128; j++) p += cp[j] * W1[j*32 + t];
    part[g][t] = p;
    __syncthreads();
    if (tid < 32){
        float s = b1[tid];
#pragma unroll
        for (int q=0;q<8;q++) s += part[q][tid];
        h[tid] = gelu_f(s);
    }
    __syncthreads();
    if (tid < 4){
        float z = b2[tid];
        for (int k=0;k<32;k++) z += h[k]*W2[k*4 + tid];
        thrs[tid] = sigm_f(z);
    }
    if (tid == 4) thrs[4] = 0.5f;   // betti threshold
}

__global__ void embed_kernel(const int* __restrict__ tok, const float* __restrict__ emb,
                             const float* __restrict__ pos, float* __restrict__ x)
{
    const long i = (long)blockIdx.x*256 + threadIdx.x;  // f32x4 index, 1,048,576 total
    const int  d4 = i & 255;
    const long bt = i >> 8;            // 0..4095
    const int  t  = (int)(bt & 2047);
    const int  token = tok[bt];
    f32x4 e = *(const f32x4*)(emb + (long)token*1024 + d4*4);
    f32x4 p = *(const f32x4*)(pos + (long)t*1024 + d4*4);
    *(f32x4*)(x + i*4) = e + p;
}

__global__ void transpose_f2b(const float* __restrict__ in, int ldin,
                              bf16* __restrict__ out, int ldout, int R, int C)
{
    __shared__ float tile[32][33];
    const int nbx = C >> 5;
    const int bx = blockIdx.x % nbx, by = blockIdx.x / nbx;
    const int tx = threadIdx.x & 31, ty = threadIdx.x >> 5; // 32x8
#pragma unroll
    for (int i=0;i<32;i+=8)
        tile[ty+i][tx] = in[(long)(by*32+ty+i)*ldin + bx*32+tx];
    __syncthreads();
#pragma unroll
    for (int i=0;i<32;i+=8)
        out[(long)(bx*32+ty+i)*ldout + by*32+tx] = (bf16)tile[tx][ty+i];
}

__global__ void rownorm_kernel(const float* __restrict__ x, bf16* __restrict__ xn,
                               bf16* __restrict__ x0b, int ld0)
{
    const long t = blockIdx.x; const int tid = threadIdx.x;
    f32x4 v = *(const f32x4*)(x + t*1024 + tid*4);
    float s = v.x*v.x + v.y*v.y + v.z*v.z + v.w*v.w;
#pragma unroll
    for (int o=32;o>0;o>>=1) s += __shfl_down(s, o);
    __shared__ float red[4];
    if ((tid&63)==0) red[tid>>6] = s;
    __syncthreads();
    const float tot = red[0]+red[1]+red[2]+red[3];
    const float inv = 1.0f / fmaxf(sqrtf(tot), 1e-12f);
    bf16x4 a, b;
    a[0]=(bf16)(v.x*inv); a[1]=(bf16)(v.y*inv); a[2]=(bf16)(v.z*inv); a[3]=(bf16)(v.w*inv);
    b[0]=(bf16)v.x; b[1]=(bf16)v.y; b[2]=(bf16)v.z; b[3]=(bf16)v.w;
    *(bf16x4*)(xn  + t*1024 + tid*4) = a;
    *(bf16x4*)(x0b + t*ld0  + tid*4) = b;
}

__global__ void degree_kernel(const bf16* __restrict__ adj, float* __restrict__ deg)
{
    const long t = blockIdx.x; const int tid = threadIdx.x;
    bf16x8 v = *(const bf16x8*)(adj + t*2048 + tid*8);
    float s = 0.f;
#pragma unroll
    for (int j=0;j<8;j++) s += (float)v[j];
#pragma unroll
    for (int o=32;o>0;o>>=1) s += __shfl_down(s, o);
    __shared__ float red[4];
    if ((tid&63)==0) red[tid>>6] = s;
    __syncthreads();
    if (tid==0) deg[t] = red[0]+red[1]+red[2]+red[3];
}

__global__ void betti_kernel(const float* __restrict__ deg, float* __restrict__ betti)
{
    const int tid = threadIdx.x;
    float s = 0.f, c = 0.f;
#pragma unroll
    for (int i=0;i<8;i++){
        const float d = deg[tid*8 + i];
        s += d;  c += (d < 0.5f) ? 1.f : 0.f;
    }
#pragma unroll
    for (int o=32;o>0;o>>=1){ s += __shfl_down(s,o); c += __shfl_down(c,o); }
    __shared__ float ss[4], cc[4];
    if ((tid&63)==0){ ss[tid>>6]=s; cc[tid>>6]=c; }
    __syncthreads();
    if (tid==0){
        const float S = ss[0]+ss[1]+ss[2]+ss[3];
        const float C = cc[0]+cc[1]+cc[2]+cc[3];
        const float ne = 0.5f*S;
        const float b1 = ne - 2048.f + C + 1.f;
        betti[0] = C;
        betti[1] = b1 > 0.f ? b1 : 0.f;
    }
}

// b1eff[j] = int_b1[j] + beta0*int_W1[1024][j] + beta1*int_W1[1025][j]
__global__ void b1eff_kernel(const float* __restrict__ ib1, const float* __restrict__ iW1,
                             const float* __restrict__ betti, float* __restrict__ out)
{
    const int j = blockIdx.x*256 + threadIdx.x;
    out[j] = ib1[j] + betti[0]*iW1[(long)1024*2048 + j] + betti[1]*iW1[(long)1025*2048 + j];
}

__global__ void f2b_kernel(const float* __restrict__ in, bf16* __restrict__ out)
{
    const long i = (long)blockIdx.x*256 + threadIdx.x;
    f32x4 a = *(const f32x4*)(in + i*8);
    f32x4 c = *(const f32x4*)(in + i*8 + 4);
    bf16x8 o;
    o[0]=(bf16)a.x; o[1]=(bf16)a.y; o[2]=(bf16)a.z; o[3]=(bf16)a.w;
    o[4]=(bf16)c.x; o[5]=(bf16)c.y; o[6]=(bf16)c.z; o[7]=(bf16)c.w;
    *(bf16x8*)(out + i*8) = o;
}

__global__ void ln_kernel(const float* __restrict__ y, const float* __restrict__ g,
                          const float* __restrict__ b, bf16* __restrict__ out)
{
    const long t = blockIdx.x; const int tid = threadIdx.x;
    f32x4 v = *(const f32x4*)(y + t*1024 + tid*4);
    float s  = v.x+v.y+v.z+v.w;
    float s2 = v.x*v.x+v.y*v.y+v.z*v.z+v.w*v.w;
#pragma unroll
    for (int o=32;o>0;o>>=1){ s += __shfl_down(s,o); s2 += __shfl_down(s2,o); }
    __shared__ float ss[4], qq[4];
    if ((tid&63)==0){ ss[tid>>6]=s; qq[tid>>6]=s2; }
    __syncthreads();
    const float S = ss[0]+ss[1]+ss[2]+ss[3], Q = qq[0]+qq[1]+qq[2]+qq[3];
    const float mu  = S * (1.f/1024.f);
    const float var = Q * (1.f/1024.f) - mu*mu;
    const float inv = rsqrtf(var + 1e-5f);
    f32x4 gv = *(const f32x4*)(g + tid*4);
    f32x4 bv = *(const f32x4*)(b + tid*4);
    bf16x4 o;
    o[0] = (bf16)((v.x - mu)*inv*gv.x + bv.x);
    o[1] = (bf16)((v.y - mu)*inv*gv.y + bv.y);
    o[2] = (bf16)((v.z - mu)*inv*gv.z + bv.z);
    o[3] = (bf16)((v.w - mu)*inv*gv.w + bv.w);
    *(bf16x4*)(out + t*1024 + tid*4) = o;
}

// ---------------------------------------------------------------------------
extern "C" void kernel_launch(void* const* d_in, const int* in_sizes, int n_in,
                              void* d_out, int out_size, void* d_ws, size_t ws_size,
                              hipStream_t stream)
{
    const int*   tokens = (const int*)  d_in[0];
    const float* cstate = (const float*)d_in[1];
    const float* embedW = (const float*)d_in[2];
    const float* posW   = (const float*)d_in[3];
    const float* thrW1  = (const float*)d_in[8];
    const float* thrb1  = (const float*)d_in[9];
    const float* thrW2  = (const float*)d_in[10];
    const float* thrb2  = (const float*)d_in[11];
    const float* simpW1 = (const float*)d_in[12];
    const float* simpb1 = (const float*)d_in[13];
    const float* simpW2 = (const float*)d_in[14];
    const float* simpb2 = (const float*)d_in[15];
    const float* intW1  = (const float*)d_in[16];
    const float* intb1  = (const float*)d_in[17];
    const float* intW2  = (const float*)d_in[18];
    const float* intb2  = (const float*)d_in[19];
    const float* lng    = (const float*)d_in[20];
    const float* lnb    = (const float*)d_in[21];
    const float* headW  = (const float*)d_in[22];
    float* out = (float*)d_out;

    size_t off = 0;
    auto carve = [&](size_t bytes) -> void* {
        void* p = (char*)d_ws + off;
        off += (bytes + 255) & ~(size_t)255;
        return p;
    };
    float* x_f32   = (float*)carve(16777216);   // [2][2048][1024] f32
    bf16*  xn      = (bf16*) carve(4194304);    // [2048][1024]
    bf16*  x0T     = (bf16*) carve(4194304);    // [1024][2048]  (contiguous after xn)
    bf16*  comb    = (bf16*) carve(8388608);    // [2048][2048]
    bf16*  adj     = (bf16*) carve(8388608);    // [2048][2048]  (contiguous after comb)
    bf16*  h1      = (bf16*) carve(4194304);    // [2048][1024]
    bf16*  xb      = (bf16*) carve(8388608);    // [4096][1024]
    bf16*  w1T     = (bf16*) carve(16777216);   // [4][1024][2048]
    bf16*  w2T     = (bf16*) carve(8388608);    // [4][1024][1024]
    bf16*  i1T     = (bf16*) carve(4194304);    // [2048][1024]
    bf16*  i2T     = (bf16*) carve(4194304);    // [1024][2048]
    bf16*  hT      = (bf16*) carve(65536000);   // [32000][1024]
    float* degree  = (float*)carve(8192);
    float* b1eff   = (float*)carve(8192);
    float* thrs    = (float*)carve(64);
    float* betti   = (float*)carve(64);
    // aliases (lifetimes disjoint):
    bf16*  h2  = comb;     // [4096][2048] over comb+adj (dead after betti/degree)
    float* yv  = x_f32;    // [4096][1024] f32 (x_f32 dead after f2b)
    bf16*  xln = xn;       // [4096][1024] over xn+x0T (dead after betti sim GEMM)

    const dim3 blk(256);
    const dim3 blk512(512);

    prep_kernel<<<1, blk, 0, stream>>>(cstate, thrW1, thrb1, thrW2, thrb2, thrs);
    embed_kernel<<<4096, blk, 0, stream>>>(tokens, embedW, posW, x_f32);

    // weight transposes (f32 -> bf16, N x K layout)
    for (int l=0;l<4;l++)
        transpose_f2b<<<(1024/32)*(2048/32), blk, 0, stream>>>(
            simpW1 + (long)l*2048*1024, 1024, w1T + (long)l*1024*2048, 2048, 2048, 1024);
    for (int l=0;l<4;l++)
        transpose_f2b<<<(1024/32)*(1024/32), blk, 0, stream>>>(
            simpW2 + (long)l*1024*1024, 1024, w2T + (long)l*1024*1024, 1024, 1024, 1024);
    transpose_f2b<<<(2048/32)*(1024/32), blk, 0, stream>>>(intW1, 2048, i1T, 1024, 1024, 2048);
    transpose_f2b<<<(1024/32)*(2048/32), blk, 0, stream>>>(intW2, 1024, i2T, 2048, 2048, 1024);
    transpose_f2b<<<(32000/32)*(1024/32), blk, 0, stream>>>(headW, 32000, hT, 1024, 1024, 32000);

    // simplex levels
    for (int l=0;l<4;l++){
        rownorm_kernel<<<2048, blk, 0, stream>>>(x_f32, xn, comb, 2048);
        transpose_f2b<<<(1024/32)*(2048/32), blk, 0, stream>>>(x_f32, 1024, x0T, 2048, 2048, 1024);
        gemm_p<128,128,2,2,EPI_ADJ><<<16*16, blk, 0, stream>>>(
            xn, xn, 2048, 2048, 1024, adj, 2048, nullptr, thrs, l, nullptr, nullptr);
        gemm_p<128,128,2,2,EPI_BF16><<<16*8, blk, 0, stream>>>(
            adj, x0T, 2048, 1024, 2048, comb + 1024, 2048, nullptr, nullptr, 0, nullptr, nullptr);
        gemm_p<128,128,2,2,EPI_GELU_BIAS><<<16*8, blk, 0, stream>>>(
            comb, w1T + (long)l*1024*2048, 2048, 1024, 2048, h1, 1024,
            simpb1 + l*1024, nullptr, 0, nullptr, nullptr);
        gemm_p<128,128,2,2,EPI_XUPD><<<16*8, blk, 0, stream>>>(
            h1, w2T + (long)l*1024*1024, 2048, 1024, 1024, nullptr, 1024,
            simpb2 + l*1024, nullptr, 0, x_f32, x_f32 + (long)2048*1024);
    }

    // betti pass
    rownorm_kernel<<<2048, blk, 0, stream>>>(x_f32, xn, comb, 2048);
    gemm_p<128,128,2,2,EPI_ADJ><<<16*16, blk, 0, stream>>>(
        xn, xn, 2048, 2048, 1024, adj, 2048, nullptr, thrs, 4, nullptr, nullptr);
    degree_kernel<<<2048, blk, 0, stream>>>(adj, degree);
    betti_kernel<<<1, blk, 0, stream>>>(degree, betti);
    b1eff_kernel<<<8, blk, 0, stream>>>(intb1, intW1, betti, b1eff);

    // integrate + LN + head
    f2b_kernel<<<2048, blk, 0, stream>>>(x_f32, xb);   // 4096x1024 -> bf16
    gemm_p<128,128,2,2,EPI_GELU_BIAS><<<32*16, blk, 0, stream>>>(
        xb, i1T, 4096, 2048, 1024, h2, 2048, b1eff, nullptr, 0, nullptr, nullptr);
    gemm_p<128,128,2,2,EPI_BIAS_F32><<<32*8, blk, 0, stream>>>(
        h2, i2T, 4096, 1024, 2048, yv, 1024, intb2, nullptr, 0, nullptr, nullptr);
    ln_kernel<<<4096, blk, 0, stream>>>(yv, lng, lnb, xln);
    gemm_p<256,256,2,4,EPI_F32><<<16*125, blk512, 0, stream>>>(
        xln, hT, 4096, 32000, 1024, out, 32000, nullptr, nullptr, 0, nullptr, nullptr);
}

// Round 5
// 900.315 us; speedup vs baseline: 1.4748x; 1.1465x over previous
//
#include <hip/hip_runtime.h>

typedef __bf16 bf16;
using bf16x8 = __attribute__((ext_vector_type(8))) __bf16;
using bf16x4 = __attribute__((ext_vector_type(4))) __bf16;
using f32x4  = __attribute__((ext_vector_type(4))) float;

#define DEV __device__ __forceinline__

DEV float gelu_f(float x){ return 0.5f*x*(1.0f+erff(x*0.7071067811865475f)); }
DEV float sigm_f(float x){ return 1.0f/(1.0f+expf(-x)); }

DEV void gload16(const bf16* g, bf16* l){
    __builtin_amdgcn_global_load_lds(
        (const __attribute__((address_space(1))) void*)g,
        (__attribute__((address_space(3))) void*)l, 16, 0, 0);
}

// ---------------------------------------------------------------------------
// Pipelined bf16 MFMA GEMM:  C[M,N] = A[M,K] @ B^T   (B given as N x K)
// Counted-vmcnt pipeline (T3/T4): 2 LDS buffers, tile t+2 staged at end of
// iter t, vmcnt(VM) at top keeps next tile's loads in flight across barriers.
// Both-sides swizzle (rule #21; conflicts=0 verified r3/r4). Fragment-read
// dedup: each A/B fragment ds_read exactly once per K-tile (r4 read 2x).
// ---------------------------------------------------------------------------
enum { EPI_ADJ=0, EPI_BF16=1, EPI_GELU_BIAS=2, EPI_XUPD=3, EPI_BIAS_F32=4, EPI_F32=5 };

template<int BM,int BN,int WM,int WN,int EPI>
__global__ __launch_bounds__(WM*WN*64, 2)
void gemm_p(const bf16* __restrict__ A, const bf16* __restrict__ B,
            int M, int N, int K, void* __restrict__ Cout, int ldc,
            const float* __restrict__ bias, const float* __restrict__ scal, int sidx,
            float* __restrict__ xu0, float* __restrict__ xu1)
{
    constexpr int THREADS = WM*WN*64;
    constexpr int MR = BM/WM/16, NR = BN/WN/16;   // fragment repeats per wave
    constexpr int ATILE = BM*64, BTILE = BN*64;   // elems per K-tile
    constexpr int RR = THREADS/8;                 // rows per staging round
    constexpr int VM = (BM+BN)/RR;                // VMEM ops in flight per tile
    __shared__ bf16 sm[2*(ATILE+BTILE)];

    const int nbm = M/BM, nbn = N/BN;
    const int nwg = nbm*nbn;                      // all grids here are %8==0
    int wg = blockIdx.x;
    wg = (wg&7)*(nwg>>3) + (wg>>3);               // T1 XCD swizzle (bijective)
    const int by = wg % nbm, bx = wg / nbm;       // M-inner for B-panel reuse
    const int tid = threadIdx.x, lane = tid&63, wid = tid>>6;
    const int wm = wid / WN, wn = wid % WN;
    const int fr = lane&15, fq = lane>>4;

    // staging: thread fills LDS linear (row=tid>>3 within round, chunk=tid&7);
    // loads pre-swizzled global chunk (skc ^ (row&7)) so LDS holds swizzled
    // layout matching the read-side XOR (involution; RR%8==0 keeps row&7 stable)
    const bf16* Ab = A + (long)(by*BM + (tid>>3))*K + (((tid&7) ^ ((tid>>3)&7))<<3);
    const bf16* Bb = B + (long)(bx*BN + (tid>>3))*K + (((tid&7) ^ ((tid>>3)&7))<<3);

    auto STAGE = [&](int tt, int cb){
        bf16* d = sm + cb*(ATILE+BTILE) + wid*512;   // wave-uniform base
        const long ko = (long)tt*64;
#pragma unroll
        for (int g=0; g<BM/RR; ++g)
            gload16(Ab + (long)g*RR*K + ko, d + g*RR*64);
#pragma unroll
        for (int g=0; g<BN/RR; ++g)
            gload16(Bb + (long)g*RR*K + ko, d + ATILE + g*RR*64);
    };

    f32x4 acc[MR][NR] = {};
    const int nt = K >> 6;

    STAGE(0,0);
    STAGE(1,1);

    for (int t=0; t<nt; ++t){
        const bf16* bufA = sm + (t&1)*(ATILE+BTILE);
        const bf16* bufB = bufA + ATILE;
        // tile t landed; next tile's VM loads stay in flight (counted, T4)
        if (t+1<nt){
            if constexpr (VM==6)      asm volatile("s_waitcnt vmcnt(6)" ::: "memory");
            else if constexpr (VM==8) asm volatile("s_waitcnt vmcnt(8)" ::: "memory");
            else                      asm volatile("s_waitcnt vmcnt(0)" ::: "memory");
        } else {
            asm volatile("s_waitcnt vmcnt(0)" ::: "memory");
        }
        __builtin_amdgcn_s_barrier();             // all waves' loads landed
        __builtin_amdgcn_sched_barrier(0);
#pragma unroll
        for (int ks=0; ks<2; ++ks){
            bf16x8 af[MR], bv[NR];
            const int ch = (((ks*4+fq) ^ (fr&7))<<3);   // read-side swizzle
#pragma unroll
            for (int j=0;j<MR;++j)
                af[j] = *(const bf16x8*)&bufA[(wm*(MR*16) + j*16 + fr)*64 + ch];
#pragma unroll
            for (int j=0;j<NR;++j)
                bv[j] = *(const bf16x8*)&bufB[(wn*(NR*16) + j*16 + fr)*64 + ch];
            __builtin_amdgcn_s_setprio(1);
#pragma unroll
            for (int mi=0;mi<MR;++mi)
#pragma unroll
            for (int ni=0;ni<NR;++ni)
                acc[mi][ni] = __builtin_amdgcn_mfma_f32_16x16x32_bf16(
                    af[mi], bv[ni], acc[mi][ni], 0,0,0);
            __builtin_amdgcn_s_setprio(0);
        }
        asm volatile("s_waitcnt lgkmcnt(0)" ::: "memory");  // reads serviced
        __builtin_amdgcn_s_barrier();             // before overwriting buf
        if (t+2<nt) STAGE(t+2, t&1);
    }

    float thr = 0.f;
    if constexpr (EPI==EPI_ADJ) thr = scal[sidx];

#pragma unroll
    for (int mi=0;mi<MR;++mi){
#pragma unroll
        for (int ni=0;ni<NR;++ni){
            const int col = bx*BN + wn*(NR*16) + ni*16 + fr;
#pragma unroll
            for (int r=0;r<4;++r){
                const int row = by*BM + wm*(MR*16) + mi*16 + fq*4 + r;
                const float v = acc[mi][ni][r];
                const long ci = (long)row*ldc + col;
                if constexpr (EPI==EPI_ADJ)       ((bf16*)Cout)[ci] = (bf16)sigm_f(10.f*(v - thr));
                else if constexpr (EPI==EPI_BF16) ((bf16*)Cout)[ci] = (bf16)v;
                else if constexpr (EPI==EPI_GELU_BIAS) ((bf16*)Cout)[ci] = (bf16)gelu_f(v + bias[col]);
                else if constexpr (EPI==EPI_BIAS_F32)  ((float*)Cout)[ci] = v + bias[col];
                else if constexpr (EPI==EPI_F32)       ((float*)Cout)[ci] = v;
                else if constexpr (EPI==EPI_XUPD){
                    const float u = 0.2f*(v + bias[col]);
                    xu0[ci] += u;  xu1[ci] += u;
                }
            }
        }
    }
}

// ---------------------------------------------------------------------------
// small kernels
// ---------------------------------------------------------------------------
__global__ void prep_kernel(const float* __restrict__ cs,
                            const float* __restrict__ W1, const float* __restrict__ b1,
                            const float* __restrict__ W2, const float* __restrict__ b2,
                            float* __restrict__ thrs)
{
    __shared__ float cp[1024];
    __shared__ float part[8][32];
    __shared__ float h[32];
    const int tid = threadIdx.x;
    for (int j = tid; j < 1024; j += 256){
        float s = 0.f;
#pragma unroll
        for (int r = 0; r < 8; r++) s += cs[r*1024 + j];
        cp[j] = s * 0.125f;
    }
    __syncthreads();
    const int t = tid & 31, g = tid >> 5;
    float p = 0.f;
    for (int j = g*128; j < g*128+128; j++) p += cp[j] * W1[j*32 + t];
    part[g][t] = p;
    __syncthreads();
    if (tid < 32){
        float s = b1[tid];
#pragma unroll
        for (int q=0;q<8;q++) s += part[q][tid];
        h[tid] = gelu_f(s);
    }
    __syncthreads();
    if (tid < 4){
        float z = b2[tid];
        for (int k=0;k<32;k++) z += h[k]*W2[k*4 + tid];
        thrs[tid] = sigm_f(z);
    }
    if (tid == 4) thrs[4] = 0.5f;   // betti threshold
}

__global__ void embed_kernel(const int* __restrict__ tok, const float* __restrict__ emb,
                             const float* __restrict__ pos, float* __restrict__ x)
{
    const long i = (long)blockIdx.x*256 + threadIdx.x;  // f32x4 index, 1,048,576 total
    const int  d4 = i & 255;
    const long bt = i >> 8;            // 0..4095
    const int  t  = (int)(bt & 2047);
    const int  token = tok[bt];
    f32x4 e = *(const f32x4*)(emb + (long)token*1024 + d4*4);
    f32x4 p = *(const f32x4*)(pos + (long)t*1024 + d4*4);
    *(f32x4*)(x + i*4) = e + p;
}

__global__ void transpose_f2b(const float* __restrict__ in, int ldin,
                              bf16* __restrict__ out, int ldout, int R, int C)
{
    __shared__ float tile[32][33];
    const int nbx = C >> 5;
    const int bx = blockIdx.x % nbx, by = blockIdx.x / nbx;
    const int tx = threadIdx.x & 31, ty = threadIdx.x >> 5; // 32x8
#pragma unroll
    for (int i=0;i<32;i+=8)
        tile[ty+i][tx] = in[(long)(by*32+ty+i)*ldin + bx*32+tx];
    __syncthreads();
#pragma unroll
    for (int i=0;i<32;i+=8)
        out[(long)(bx*32+ty+i)*ldout + by*32+tx] = (bf16)tile[tx][ty+i];
}

__global__ void rownorm_kernel(const float* __restrict__ x, bf16* __restrict__ xn,
                               bf16* __restrict__ x0b, int ld0)
{
    const long t = blockIdx.x; const int tid = threadIdx.x;
    f32x4 v = *(const f32x4*)(x + t*1024 + tid*4);
    float s = v.x*v.x + v.y*v.y + v.z*v.z + v.w*v.w;
#pragma unroll
    for (int o=32;o>0;o>>=1) s += __shfl_down(s, o);
    __shared__ float red[4];
    if ((tid&63)==0) red[tid>>6] = s;
    __syncthreads();
    const float tot = red[0]+red[1]+red[2]+red[3];
    const float inv = 1.0f / fmaxf(sqrtf(tot), 1e-12f);
    bf16x4 a, b;
    a[0]=(bf16)(v.x*inv); a[1]=(bf16)(v.y*inv); a[2]=(bf16)(v.z*inv); a[3]=(bf16)(v.w*inv);
    b[0]=(bf16)v.x; b[1]=(bf16)v.y; b[2]=(bf16)v.z; b[3]=(bf16)v.w;
    *(bf16x4*)(xn  + t*1024 + tid*4) = a;
    *(bf16x4*)(x0b + t*ld0  + tid*4) = b;
}

__global__ void degree_kernel(const bf16* __restrict__ adj, float* __restrict__ deg)
{
    const long t = blockIdx.x; const int tid = threadIdx.x;
    bf16x8 v = *(const bf16x8*)(adj + t*2048 + tid*8);
    float s = 0.f;
#pragma unroll
    for (int j=0;j<8;j++) s += (float)v[j];
#pragma unroll
    for (int o=32;o>0;o>>=1) s += __shfl_down(s, o);
    __shared__ float red[4];
    if ((tid&63)==0) red[tid>>6] = s;
    __syncthreads();
    if (tid==0) deg[t] = red[0]+red[1]+red[2]+red[3];
}

__global__ void betti_kernel(const float* __restrict__ deg, float* __restrict__ betti)
{
    const int tid = threadIdx.x;
    float s = 0.f, c = 0.f;
#pragma unroll
    for (int i=0;i<8;i++){
        const float d = deg[tid*8 + i];
        s += d;  c += (d < 0.5f) ? 1.f : 0.f;
    }
#pragma unroll
    for (int o=32;o>0;o>>=1){ s += __shfl_down(s,o); c += __shfl_down(c,o); }
    __shared__ float ss[4], cc[4];
    if ((tid&63)==0){ ss[tid>>6]=s; cc[tid>>6]=c; }
    __syncthreads();
    if (tid==0){
        const float S = ss[0]+ss[1]+ss[2]+ss[3];
        const float C = cc[0]+cc[1]+cc[2]+cc[3];
        const float ne = 0.5f*S;
        const float b1 = ne - 2048.f + C + 1.f;
        betti[0] = C;
        betti[1] = b1 > 0.f ? b1 : 0.f;
    }
}

// b1eff[j] = int_b1[j] + beta0*int_W1[1024][j] + beta1*int_W1[1025][j]
__global__ void b1eff_kernel(const float* __restrict__ ib1, const float* __restrict__ iW1,
                             const float* __restrict__ betti, float* __restrict__ out)
{
    const int j = blockIdx.x*256 + threadIdx.x;
    out[j] = ib1[j] + betti[0]*iW1[(long)1024*2048 + j] + betti[1]*iW1[(long)1025*2048 + j];
}

__global__ void f2b_kernel(const float* __restrict__ in, bf16* __restrict__ out)
{
    const long i = (long)blockIdx.x*256 + threadIdx.x;
    f32x4 a = *(const f32x4*)(in + i*8);
    f32x4 c = *(const f32x4*)(in + i*8 + 4);
    bf16x8 o;
    o[0]=(bf16)a.x; o[1]=(bf16)a.y; o[2]=(bf16)a.z; o[3]=(bf16)a.w;
    o[4]=(bf16)c.x; o[5]=(bf16)c.y; o[6]=(bf16)c.z; o[7]=(bf16)c.w;
    *(bf16x8*)(out + i*8) = o;
}

__global__ void ln_kernel(const float* __restrict__ y, const float* __restrict__ g,
                          const float* __restrict__ b, bf16* __restrict__ out)
{
    const long t = blockIdx.x; const int tid = threadIdx.x;
    f32x4 v = *(const f32x4*)(y + t*1024 + tid*4);
    float s  = v.x+v.y+v.z+v.w;
    float s2 = v.x*v.x+v.y*v.y+v.z*v.z+v.w*v.w;
#pragma unroll
    for (int o=32;o>0;o>>=1){ s += __shfl_down(s,o); s2 += __shfl_down(s2,o); }
    __shared__ float ss[4], qq[4];
    if ((tid&63)==0){ ss[tid>>6]=s; qq[tid>>6]=s2; }
    __syncthreads();
    const float S = ss[0]+ss[1]+ss[2]+ss[3], Q = qq[0]+qq[1]+qq[2]+qq[3];
    const float mu  = S * (1.f/1024.f);
    const float var = Q * (1.f/1024.f) - mu*mu;
    const float inv = rsqrtf(var + 1e-5f);
    f32x4 gv = *(const f32x4*)(g + tid*4);
    f32x4 bv = *(const f32x4*)(b + tid*4);
    bf16x4 o;
    o[0] = (bf16)((v.x - mu)*inv*gv.x + bv.x);
    o[1] = (bf16)((v.y - mu)*inv*gv.y + bv.y);
    o[2] = (bf16)((v.z - mu)*inv*gv.z + bv.z);
    o[3] = (bf16)((v.w - mu)*inv*gv.w + bv.w);
    *(bf16x4*)(out + t*1024 + tid*4) = o;
}

// ---------------------------------------------------------------------------
extern "C" void kernel_launch(void* const* d_in, const int* in_sizes, int n_in,
                              void* d_out, int out_size, void* d_ws, size_t ws_size,
                              hipStream_t stream)
{
    const int*   tokens = (const int*)  d_in[0];
    const float* cstate = (const float*)d_in[1];
    const float* embedW = (const float*)d_in[2];
    const float* posW   = (const float*)d_in[3];
    const float* thrW1  = (const float*)d_in[8];
    const float* thrb1  = (const float*)d_in[9];
    const float* thrW2  = (const float*)d_in[10];
    const float* thrb2  = (const float*)d_in[11];
    const float* simpW1 = (const float*)d_in[12];
    const float* simpb1 = (const float*)d_in[13];
    const float* simpW2 = (const float*)d_in[14];
    const float* simpb2 = (const float*)d_in[15];
    const float* intW1  = (const float*)d_in[16];
    const float* intb1  = (const float*)d_in[17];
    const float* intW2  = (const float*)d_in[18];
    const float* intb2  = (const float*)d_in[19];
    const float* lng    = (const float*)d_in[20];
    const float* lnb    = (const float*)d_in[21];
    const float* headW  = (const float*)d_in[22];
    float* out = (float*)d_out;

    size_t off = 0;
    auto carve = [&](size_t bytes) -> void* {
        void* p = (char*)d_ws + off;
        off += (bytes + 255) & ~(size_t)255;
        return p;
    };
    float* x_f32   = (float*)carve(16777216);   // [2][2048][1024] f32
    bf16*  xn      = (bf16*) carve(4194304);    // [2048][1024]
    bf16*  x0T     = (bf16*) carve(4194304);    // [1024][2048]  (contiguous after xn)
    bf16*  comb    = (bf16*) carve(8388608);    // [2048][2048]
    bf16*  adj     = (bf16*) carve(8388608);    // [2048][2048]  (contiguous after comb)
    bf16*  h1      = (bf16*) carve(4194304);    // [2048][1024]
    bf16*  xb      = (bf16*) carve(8388608);    // [4096][1024]
    bf16*  w1T     = (bf16*) carve(16777216);   // [4][1024][2048]
    bf16*  w2T     = (bf16*) carve(8388608);    // [4][1024][1024]
    bf16*  i1T     = (bf16*) carve(4194304);    // [2048][1024]
    bf16*  i2T     = (bf16*) carve(4194304);    // [1024][2048]
    bf16*  hT      = (bf16*) carve(65536000);   // [32000][1024]
    float* degree  = (float*)carve(8192);
    float* b1eff   = (float*)carve(8192);
    float* thrs    = (float*)carve(64);
    float* betti   = (float*)carve(64);
    // aliases (lifetimes disjoint):
    bf16*  h2  = comb;     // [4096][2048] over comb+adj (dead after betti/degree)
    float* yv  = x_f32;    // [4096][1024] f32 (x_f32 dead after f2b)
    bf16*  xln = xn;       // [4096][1024] over xn+x0T (dead after betti sim GEMM)

    const dim3 blk(256);
    const dim3 blk512(512);

    prep_kernel<<<1, blk, 0, stream>>>(cstate, thrW1, thrb1, thrW2, thrb2, thrs);
    embed_kernel<<<4096, blk, 0, stream>>>(tokens, embedW, posW, x_f32);

    // weight transposes (f32 -> bf16, N x K layout)
    for (int l=0;l<4;l++)
        transpose_f2b<<<(1024/32)*(2048/32), blk, 0, stream>>>(
            simpW1 + (long)l*2048*1024, 1024, w1T + (long)l*1024*2048, 2048, 2048, 1024);
    for (int l=0;l<4;l++)
        transpose_f2b<<<(1024/32)*(1024/32), blk, 0, stream>>>(
            simpW2 + (long)l*1024*1024, 1024, w2T + (long)l*1024*1024, 1024, 1024, 1024);
    transpose_f2b<<<(2048/32)*(1024/32), blk, 0, stream>>>(intW1, 2048, i1T, 1024, 1024, 2048);
    transpose_f2b<<<(1024/32)*(2048/32), blk, 0, stream>>>(intW2, 1024, i2T, 2048, 2048, 1024);
    transpose_f2b<<<(32000/32)*(1024/32), blk, 0, stream>>>(headW, 32000, hT, 1024, 1024, 32000);

    // simplex levels
    for (int l=0;l<4;l++){
        rownorm_kernel<<<2048, blk, 0, stream>>>(x_f32, xn, comb, 2048);
        transpose_f2b<<<(1024/32)*(2048/32), blk, 0, stream>>>(x_f32, 1024, x0T, 2048, 2048, 1024);
        gemm_p<128,128,2,2,EPI_ADJ><<<16*16, blk, 0, stream>>>(
            xn, xn, 2048, 2048, 1024, adj, 2048, nullptr, thrs, l, nullptr, nullptr);
        gemm_p<64,128,2,2,EPI_BF16><<<32*8, blk, 0, stream>>>(
            adj, x0T, 2048, 1024, 2048, comb + 1024, 2048, nullptr, nullptr, 0, nullptr, nullptr);
        gemm_p<64,128,2,2,EPI_GELU_BIAS><<<32*8, blk, 0, stream>>>(
            comb, w1T + (long)l*1024*2048, 2048, 1024, 2048, h1, 1024,
            simpb1 + l*1024, nullptr, 0, nullptr, nullptr);
        gemm_p<64,128,2,2,EPI_XUPD><<<32*8, blk, 0, stream>>>(
            h1, w2T + (long)l*1024*1024, 2048, 1024, 1024, nullptr, 1024,
            simpb2 + l*1024, nullptr, 0, x_f32, x_f32 + (long)2048*1024);
    }

    // betti pass
    rownorm_kernel<<<2048, blk, 0, stream>>>(x_f32, xn, comb, 2048);
    gemm_p<128,128,2,2,EPI_ADJ><<<16*16, blk, 0, stream>>>(
        xn, xn, 2048, 2048, 1024, adj, 2048, nullptr, thrs, 4, nullptr, nullptr);
    degree_kernel<<<2048, blk, 0, stream>>>(adj, degree);
    betti_kernel<<<1, blk, 0, stream>>>(degree, betti);
    b1eff_kernel<<<8, blk, 0, stream>>>(intb1, intW1, betti, b1eff);

    // integrate + LN + head
    f2b_kernel<<<2048, blk, 0, stream>>>(x_f32, xb);   // 4096x1024 -> bf16
    gemm_p<128,128,2,2,EPI_GELU_BIAS><<<32*16, blk, 0, stream>>>(
        xb, i1T, 4096, 2048, 1024, h2, 2048, b1eff, nullptr, 0, nullptr, nullptr);
    gemm_p<128,128,2,2,EPI_BIAS_F32><<<32*8, blk, 0, stream>>>(
        h2, i2T, 4096, 1024, 2048, yv, 1024, intb2, nullptr, 0, nullptr, nullptr);
    ln_kernel<<<4096, blk, 0, stream>>>(yv, lng, lnb, xln);
    gemm_p<256,256,2,4,EPI_F32><<<16*125, blk512, 0, stream>>>(
        xln, hT, 4096, 32000, 1024, out, 32000, nullptr, nullptr, 0, nullptr, nullptr);
}